// Round 6
// baseline (1199.910 us; speedup 1.0000x reference)
//
#include <hip/hip_runtime.h>

// Problem constants (fixed by setup_inputs in the reference).
#define NIMG 4
#define CCH  256
#define HDIM 200
#define WDIM 272
#define OSZ  7

// ---------------------------------------------------------------------------
// K1: column prefix scan in NATIVE layout.
//   colint[n][c][h][w] = sum_{h'<=h} fm[n][c][h'][w]
// Thread = one (n,c,w) column; consecutive threads -> consecutive w, so both
// the fm reads and colint writes are stride-1 coalesced (no transpose, no
// RMW: separate src/dst buffers). 278,528 threads = 1088 blocks = ~17
// waves/CU. Unroll-8: 8 independent loads in flight per dependent add chain.
// ---------------------------------------------------------------------------
__global__ __launch_bounds__(256) void k_colscan_n(const float* __restrict__ fm,
                                                   float* __restrict__ colint) {
    const int gid = blockIdx.x * 256 + threadIdx.x;   // 0 .. 4*256*272-1
    const int w   = gid % WDIM;
    const int nc  = gid / WDIM;                       // n*CCH + c

    const float* src = fm     + (size_t)nc * HDIM * WDIM + w;
    float*       dst = colint + (size_t)nc * HDIM * WDIM + w;

    float run = 0.0f;
    for (int h = 0; h < HDIM; h += 8) {               // 200 % 8 == 0
        float v[8];
#pragma unroll
        for (int k = 0; k < 8; ++k) v[k] = src[(size_t)(h + k) * WDIM];
#pragma unroll
        for (int k = 0; k < 8; ++k) { run += v[k]; dst[(size_t)(h + k) * WDIM] = run; }
    }
}

// ---------------------------------------------------------------------------
// K2: pooling directly from the column-integral (native layout).
// bin(i,j) sum = sum_{w in [wsj,wej)} ( colint[he_i-1][w] - colint[hs_i-1][w] )
// Block = ROI r (1000 blocks), 4 waves. Wave processes tasks t=(c,i); lanes
// run along w so row reads are coalesced float4 chunks. Within a chunk:
// per-lane 4-element local scan + 6-step shfl wave scan gives the global
// prefix P(w); each j-bin (owned by lane j<7) extracts P(wej-1) and P(wsj-1)
// via bpermute (handles torch's overlapping ceil/floor bins exactly; bins
// may share one element, prefix differences don't care).
// ---------------------------------------------------------------------------
__global__ __launch_bounds__(256) void k_poolw(const float* __restrict__ colint,
                                               const int* __restrict__ rois,
                                               float* __restrict__ out, int R) {
    const int r    = blockIdx.x;
    const int lane = threadIdx.x & 63;
    const int wave = threadIdx.x >> 6;

    const int* rp = rois + r * 5;
    const int n  = rp[0];
    const int x1 = rp[1], y1 = rp[2], x2 = rp[3], y2 = rp[4];
    const int h_in = y2 - y1 + 1;
    const int w_in = x2 - x1 + 1;

    if (threadIdx.x == 0) out[r] = (float)n;          // img_idx output (exact for n<2^24)

    // Per-lane w-bin boundaries: lane l<7 owns bin j=l.
    const int jl   = (lane < OSZ) ? lane : 0;
    const int wsl  = x1 + (jl * w_in) / OSZ;
    const int wel  = x1 + ((jl + 1) * w_in + OSZ - 1) / OSZ;
    const int loTgt = wsl - 1;                        // prefix position for lo (may be x1-1 -> lo=0)
    const int hiTgt = wel - 1;                        // always in [x1, x2]

    const int w0start = x1 & ~3;                      // 16B-aligned chunk origin
    const int nchunk  = (x2 - w0start) / 256 + 1;     // <= 2

    const size_t img_base = (size_t)n * CCH * HDIM * WDIM;

    for (int t = wave; t < CCH * OSZ; t += 4) {
        const int c = t / OSZ;
        const int i = t - c * OSZ;
        const int hs = y1 + (i * h_in) / OSZ;
        const int he = y1 + ((i + 1) * h_in + OSZ - 1) / OSZ;
        const float inv_area = 1.0f / (float)((he - hs) * (wel - wsl)); // lane-specific

        const float* rowT = colint + img_base + ((size_t)c * HDIM + (he - 1)) * WDIM;
        const bool hasB = (hs > 0);
        const float* rowB = hasB
            ? colint + img_base + ((size_t)c * HDIM + (hs - 1)) * WDIM
            : rowT;                                   // dummy (masked out below)

        float lo = 0.0f, hi = 0.0f, runbase = 0.0f;

        for (int ch = 0; ch < nchunk; ++ch) {
            const int w0 = w0start + ch * 256;
            const int lw = w0 + lane * 4;             // this lane's first w (aligned)
            const bool act = (lw <= x2);              // lw<=x2<=271 and lw%4==0 => lw+3<=271: in-row
            const int addr = act ? lw : 0;

            float4 tv = *reinterpret_cast<const float4*>(rowT + addr);
            float4 bv = *reinterpret_cast<const float4*>(rowB + addr);
            if (!hasB) bv = make_float4(0.f, 0.f, 0.f, 0.f);

            // masked per-element diff (zero outside [x1,x2] or inactive lane)
            float d0 = (act && lw     >= x1 && lw     <= x2) ? tv.x - bv.x : 0.0f;
            float d1 = (act && lw + 1 >= x1 && lw + 1 <= x2) ? tv.y - bv.y : 0.0f;
            float d2 = (act && lw + 2 >= x1 && lw + 2 <= x2) ? tv.z - bv.z : 0.0f;
            float d3 = (act && lw + 3 >= x1 && lw + 3 <= x2) ? tv.w - bv.w : 0.0f;

            // local inclusive scan over the lane's 4 elements
            const float s0 = d0, s1 = s0 + d1, s2 = s1 + d2, s3 = s2 + d3;

            // wave inclusive scan of lane totals -> exclusive prefix
            const float tot = s3;
            float inc = tot;
#pragma unroll
            for (int off = 1; off < 64; off <<= 1) {
                float y = __shfl_up(inc, off);
                if (lane >= off) inc += y;
            }
            const float excl = inc - tot;

            // global prefixes of this lane's 4 positions
            const float p0 = runbase + excl + s0;
            const float p1 = runbase + excl + s1;
            const float p2 = runbase + excl + s2;
            const float p3 = runbase + excl + s3;

            const float chunkTot = __shfl(inc, 63);   // includes masked zeros: harmless

            // boundary extraction — all lanes execute the shuffles (full exec),
            // results only committed when the target falls in this chunk.
            {
                const int off_ = loTgt - w0;
                const int sl   = (off_ >> 2) & 63;
                const int k    = off_ & 3;
                const float q0 = __shfl(p0, sl), q1 = __shfl(p1, sl);
                const float q2 = __shfl(p2, sl), q3 = __shfl(p3, sl);
                const float v01 = (k & 1) ? q1 : q0;
                const float v23 = (k & 1) ? q3 : q2;
                if (off_ >= 0 && off_ < 256) lo = (k & 2) ? v23 : v01;
            }
            {
                const int off_ = hiTgt - w0;
                const int sl   = (off_ >> 2) & 63;
                const int k    = off_ & 3;
                const float q0 = __shfl(p0, sl), q1 = __shfl(p1, sl);
                const float q2 = __shfl(p2, sl), q3 = __shfl(p3, sl);
                const float v01 = (k & 1) ? q1 : q0;
                const float v23 = (k & 1) ? q3 : q2;
                if (off_ >= 0 && off_ < 256) hi = (k & 2) ? v23 : v01;
            }
            runbase += chunkTot;
        }

        if (lane < OSZ) {
            // out layout: img_idx[R] then out[r][c][i][j]
            out[(size_t)R + (((size_t)r * CCH + c) * OSZ + i) * OSZ + lane] =
                (hi - lo) * inv_area;
        }
    }
}

// ---------------------------------------------------------------------------
// Fallback: direct summation (no workspace). Block = (roi,i,j), thread = c.
// ---------------------------------------------------------------------------
__global__ __launch_bounds__(256) void k_direct(const float* __restrict__ fm,
                                                const int* __restrict__ rois,
                                                float* __restrict__ out, int R) {
    const int b  = blockIdx.x;
    const int r  = b / (OSZ * OSZ);
    const int ij = b % (OSZ * OSZ);
    const int i  = ij / OSZ;
    const int j  = ij % OSZ;
    const int c  = threadIdx.x;

    const int* rp = rois + r * 5;
    const int n  = rp[0];
    const int x1 = rp[1], y1 = rp[2], x2 = rp[3], y2 = rp[4];
    const int h_in = y2 - y1 + 1;
    const int w_in = x2 - x1 + 1;

    const int hs = y1 + (i * h_in) / OSZ;
    const int he = y1 + ((i + 1) * h_in + OSZ - 1) / OSZ;
    const int ws = x1 + (j * w_in) / OSZ;
    const int we = x1 + ((j + 1) * w_in + OSZ - 1) / OSZ;

    const float inv_area = 1.0f / (float)((he - hs) * (we - ws));

    const float* p = fm + (size_t)(n * CCH + c) * HDIM * WDIM;
    float acc = 0.0f;
    for (int h = hs; h < he; ++h) {
        const float* row = p + (size_t)h * WDIM;
        for (int w = ws; w < we; ++w) acc += row[w];
    }
    out[R + (((size_t)r * CCH + c) * OSZ + i) * OSZ + j] = acc * inv_area;

    if (ij == 0 && c == 0) out[r] = (float)n;
}

extern "C" void kernel_launch(void* const* d_in, const int* in_sizes, int n_in,
                              void* d_out, int out_size, void* d_ws, size_t ws_size,
                              hipStream_t stream) {
    const float* fm  = (const float*)d_in[0];
    const int* rois  = (const int*)d_in[1];
    float* out       = (float*)d_out;
    const int R      = in_sizes[1] / 5;   // 1000

    const size_t need = (size_t)NIMG * CCH * HDIM * WDIM * sizeof(float); // 222.8 MB

    if (ws_size >= need) {
        float* colint = (float*)d_ws;
        k_colscan_n<<<(NIMG * CCH * WDIM) / 256, 256, 0, stream>>>(fm, colint);
        k_poolw<<<R, 256, 0, stream>>>(colint, rois, out, R);
    } else {
        k_direct<<<R * OSZ * OSZ, 256, 0, stream>>>(fm, rois, out, R);
    }
}